// Round 4
// baseline (342.006 us; speedup 1.0000x reference)
//
#include <hip/hip_runtime.h>
#include <cstdint>

#define NN 100000
#define NE 1600000
#define NG 64
#define NH 128
#define NC 10
#define EPSV 1e-5f

#define NB 782                       // (NN+127)>>7 coarse buckets (128 nodes each)
#define NBLK 512                     // histogram/scatter blocks
#define EPB ((NE + NBLK - 1) / NBLK) // 3125 edges per block
#define NSCAN (NB * NBLK)            // 400384, divisible by 1024
#define NSB (NSCAN / 1024)           // 391 scan blocks
#define FINE_CAP 6144                // LDS edge capacity per fine tile
#define PLU ((size_t)NN * 32)        // plane stride in uints (64 feats = 32 uints)

typedef __attribute__((ext_vector_type(8))) short bf16x8;
typedef __attribute__((ext_vector_type(4))) float f32x4;

__device__ __forceinline__ ushort f2b(float f) {
  uint u = __builtin_bit_cast(uint, f);
  u = (u + 0x7FFFu + ((u >> 16) & 1u)) >> 16;
  return (ushort)u;
}
__device__ __forceinline__ float b2f(ushort h) {
  return __builtin_bit_cast(float, ((uint)h) << 16);
}
__device__ __forceinline__ float lo2f(uint v) { return __builtin_bit_cast(float, v << 16); }
__device__ __forceinline__ float hi2f(uint v) { return __builtin_bit_cast(float, v & 0xFFFF0000u); }

// ---------------- graph prep: counting sort by destination ----------------

__global__ __launch_bounds__(128) void k_gstart2(const int* __restrict__ batch,
                                                 int* __restrict__ gstart, int* __restrict__ counts) {
  __shared__ int lb[NG + 1];
  int t = threadIdx.x;
  if (t <= NG) {                      // first index with batch[i] >= t (batch is sorted)
    int lo = 0, hi = NN;
    while (lo < hi) { int mid = (lo + hi) >> 1; if (batch[mid] < t) lo = mid + 1; else hi = mid; }
    lb[t] = lo;
  }
  __syncthreads();
  if (t < NG) { gstart[t] = lb[t]; counts[t] = lb[t + 1] - lb[t]; }
  if (t == 0) gstart[NG] = NN;
}

__global__ __launch_bounds__(256) void k_hist(const int* __restrict__ ei, int* __restrict__ ghist) {
  __shared__ int h[NB];
  int t = threadIdx.x, blk = blockIdx.x;
  for (int i = t; i < NB; i += 256) h[i] = 0;
  __syncthreads();
  int e0 = blk * EPB, e1 = min(NE, e0 + EPB);
  for (int e = e0 + t; e < e1; e += 256) atomicAdd(&h[ei[NE + e] >> 7], 1);
  __syncthreads();
  for (int i = t; i < NB; i += 256) ghist[i * NBLK + blk] = h[i];
}

__global__ __launch_bounds__(256) void k_scan1g(int* __restrict__ data, int* __restrict__ bsums) {
  __shared__ int sh[256];
  int t = threadIdx.x;
  int base = blockIdx.x * 1024 + t * 4;
  int4 v = *reinterpret_cast<const int4*>(data + base);
  int s = v.x + v.y + v.z + v.w;
  sh[t] = s;
  __syncthreads();
  for (int o = 1; o < 256; o <<= 1) {
    int x = (t >= o) ? sh[t - o] : 0;
    __syncthreads();
    sh[t] += x;
    __syncthreads();
  }
  int ex = sh[t] - s;
  int4 o4;
  o4.x = ex; o4.y = ex + v.x; o4.z = ex + v.x + v.y; o4.w = ex + v.x + v.y + v.z;
  *reinterpret_cast<int4*>(data + base) = o4;
  if (t == 255) bsums[blockIdx.x] = sh[255];
}

__global__ __launch_bounds__(512) void k_scan2(int* bsums, int nb) {
  __shared__ int sh[512];
  int t = threadIdx.x;
  int v = (t < nb) ? bsums[t] : 0;
  sh[t] = v;
  __syncthreads();
  for (int o = 1; o < 512; o <<= 1) {
    int x = (t >= o) ? sh[t - o] : 0;
    __syncthreads();
    sh[t] += x;
    __syncthreads();
  }
  if (t < nb) bsums[t] = sh[t] - v;   // exclusive
}

__global__ __launch_bounds__(256) void k_scan3g(int* __restrict__ data, const int* __restrict__ bsums) {
  int t = threadIdx.x;
  int base = blockIdx.x * 1024 + t * 4;
  int add = bsums[blockIdx.x];
  int4 v = *reinterpret_cast<int4*>(data + base);
  v.x += add; v.y += add; v.z += add; v.w += add;
  *reinterpret_cast<int4*>(data + base) = v;
}

__global__ __launch_bounds__(256) void k_scatter(const int* __restrict__ ei, const int* __restrict__ ghist,
                                                 int2* __restrict__ tmp) {
  __shared__ int cur[NB];
  int t = threadIdx.x, blk = blockIdx.x;
  for (int i = t; i < NB; i += 256) cur[i] = ghist[i * NBLK + blk];
  __syncthreads();
  int e0 = blk * EPB, e1 = min(NE, e0 + EPB);
  for (int e = e0 + t; e < e1; e += 256) {
    int d = ei[NE + e], s = ei[e];
    int p = atomicAdd(&cur[d >> 7], 1);   // LDS atomic (fast, block-local)
    tmp[p] = make_int2(d, s);
  }
}

// fine bucket: build per-node deg/offs/dis + CSR with SORTED sources per row
__global__ __launch_bounds__(256) void k_fine(const int2* __restrict__ tmp, const int* __restrict__ ghist,
                                              int* __restrict__ deg, int* __restrict__ offs,
                                              float* __restrict__ dis, int* __restrict__ csr) {
  __shared__ int fh[128], fsc[128], fc[128];
  __shared__ int sc[FINE_CAP];
  int b = blockIdx.x, t = threadIdx.x;
  int bs = ghist[b * NBLK];
  int be = (b + 1 < NB) ? ghist[(b + 1) * NBLK] : NE;
  int tile = be - bs;
  if (t < 128) fh[t] = 0;
  __syncthreads();
  for (int e = bs + t; e < be; e += 256) atomicAdd(&fh[tmp[e].x & 127], 1);
  __syncthreads();
  if (t < 128) fsc[t] = fh[t];
  __syncthreads();
  for (int o = 1; o < 128; o <<= 1) {
    int x = 0;
    if (t < 128 && t >= o) x = fsc[t - o];
    __syncthreads();
    if (t < 128) fsc[t] += x;
    __syncthreads();
  }
  if (t < 128) {
    int ex = fsc[t] - fh[t];
    int node = b * 128 + t;
    fc[t] = ex;                       // LOCAL exclusive offset (LDS path)
    if (node < NN) {
      deg[node] = fh[t];
      offs[node] = bs + ex;
      dis[node] = rsqrtf((float)(fh[t] + 1));   // +1 self-loop
    }
  }
  __syncthreads();
  if (tile <= FINE_CAP) {
    for (int e = bs + t; e < be; e += 256) {
      int2 ds = tmp[e];
      int p = atomicAdd(&fc[ds.x & 127], 1);
      sc[p] = ds.y;
    }
    __syncthreads();
    if (t < 128) {                    // insertion-sort each row (sources ascending)
      int o = fsc[t] - fh[t], d = fh[t];
      for (int i = 1; i < d; ++i) {
        int key = sc[o + i];
        int j = i - 1;
        while (j >= 0 && sc[o + j] > key) { sc[o + j + 1] = sc[o + j]; --j; }
        sc[o + j + 1] = key;
      }
    }
    __syncthreads();
    for (int e = t; e < tile; e += 256) csr[bs + e] = sc[e];
  } else {                            // fallback: global scatter + global sort
    if (t < 128) fc[t] = bs + fsc[t] - fh[t];
    __syncthreads();
    for (int e = bs + t; e < be; e += 256) {
      int2 ds = tmp[e];
      int p = atomicAdd(&fc[ds.x & 127], 1);
      csr[p] = ds.y;
    }
    __syncthreads();
    if (t < 128 && b * 128 + t < NN) {
      int o = bs + fsc[t] - fh[t], d = fh[t];
      for (int i = 1; i < d; ++i) {
        int key = csr[o + i];
        int j = i - 1;
        while (j >= 0 && csr[o + j] > key) { csr[o + j + 1] = csr[o + j]; --j; }
        csr[o + j + 1] = key;
      }
    }
  }
}

// ---------------- W pre-pack: fragment-major bf16 B-operand (both layers) ----------------
// WF[(n*4+ks)*64 + lane][j] = W[k][col], col = n*16 + (lane&15), k = ks*32 + (lane>>4)*8 + j
__global__ __launch_bounds__(256) void k_prepw(const float* __restrict__ W1, ushort* __restrict__ WF1,
                                               const float* __restrict__ W2, ushort* __restrict__ WF2) {
  int tt = blockIdx.x * 256 + threadIdx.x;
  if (tt >= 4096) return;
  const float* W = (tt < 2048) ? W1 : W2;
  ushort* WF = (tt < 2048) ? WF1 : WF2;
  int t = tt & 2047;
  int lane = t & 63, nk = t >> 6;
  int n = nk >> 2, ks = nk & 3;
  int col = n * 16 + (lane & 15);
  int k0 = ks * 32 + (lane >> 4) * 8;
#pragma unroll
  for (int j = 0; j < 8; ++j) WF[(size_t)t * 8 + j] = f2b(W[(k0 + j) * NH + col]);
}

// ---------------- MFMA GEMM: hs = (norm?(X) @ W) * dis  (bf16 out, 2-plane layout) ----------------
// Wave = 16 rows x 128 cols. Block = 4 waves = 64 rows. No LDS.
template <bool NORM>
__global__ __launch_bounds__(256) void k_gemm(const void* __restrict__ Xv, const ushort* __restrict__ WF,
                                              const float* __restrict__ dis, const int* __restrict__ batch,
                                              const float* __restrict__ Aaff, const float* __restrict__ Baff,
                                              ushort* __restrict__ out) {
  int t = threadIdx.x;
  int w = t >> 6, lane = t & 63;
  int r0 = blockIdx.x * 64 + w * 16;
  int arow = r0 + (lane & 15);
  int khi = lane >> 4;                    // 0..3
  int arowc = (arow < NN) ? arow : (NN - 1);

  f32x4 acc[8];
#pragma unroll
  for (int n = 0; n < 8; ++n) acc[n] = (f32x4){0.f, 0.f, 0.f, 0.f};

  int g = 0;
  if (NORM) g = batch[arowc];
  const bf16x8* WFv = reinterpret_cast<const bf16x8*>(WF);

#pragma unroll
  for (int ks = 0; ks < 4; ++ks) {
    int k0 = ks * 32 + khi * 8;
    bf16x8 a;
    if (!NORM) {
      const float* X = (const float*)Xv;
      float4 x0 = *reinterpret_cast<const float4*>(X + (size_t)arowc * NH + k0);
      float4 x1 = *reinterpret_cast<const float4*>(X + (size_t)arowc * NH + k0 + 4);
      a[0] = (short)f2b(x0.x); a[1] = (short)f2b(x0.y); a[2] = (short)f2b(x0.z); a[3] = (short)f2b(x0.w);
      a[4] = (short)f2b(x1.x); a[5] = (short)f2b(x1.y); a[6] = (short)f2b(x1.z); a[7] = (short)f2b(x1.w);
    } else {
      const ushort* X = (const ushort*)Xv;   // 2-plane bf16
      const ushort* Xp = X + (size_t)(k0 >> 6) * NN * 64 + (size_t)arowc * 64 + (k0 & 63);
      bf16x8 xr = *reinterpret_cast<const bf16x8*>(Xp);
      float4 A0 = *reinterpret_cast<const float4*>(Aaff + g * NH + k0);
      float4 A1 = *reinterpret_cast<const float4*>(Aaff + g * NH + k0 + 4);
      float4 B0 = *reinterpret_cast<const float4*>(Baff + g * NH + k0);
      float4 B1 = *reinterpret_cast<const float4*>(Baff + g * NH + k0 + 4);
      a[0] = (short)f2b(fmaf(A0.x, b2f((ushort)xr[0]), B0.x));
      a[1] = (short)f2b(fmaf(A0.y, b2f((ushort)xr[1]), B0.y));
      a[2] = (short)f2b(fmaf(A0.z, b2f((ushort)xr[2]), B0.z));
      a[3] = (short)f2b(fmaf(A0.w, b2f((ushort)xr[3]), B0.w));
      a[4] = (short)f2b(fmaf(A1.x, b2f((ushort)xr[4]), B1.x));
      a[5] = (short)f2b(fmaf(A1.y, b2f((ushort)xr[5]), B1.y));
      a[6] = (short)f2b(fmaf(A1.z, b2f((ushort)xr[6]), B1.z));
      a[7] = (short)f2b(fmaf(A1.w, b2f((ushort)xr[7]), B1.w));
    }
#pragma unroll
    for (int n = 0; n < 8; ++n) {
      bf16x8 b = WFv[(n * 4 + ks) * 64 + lane];
      acc[n] = __builtin_amdgcn_mfma_f32_16x16x32_bf16(a, b, acc[n], 0, 0, 0);
    }
  }

  // D: col = n*16 + (lane&15), row = r0 + khi*4 + reg; write into 2-plane layout
  int colb = lane & 15;
#pragma unroll
  for (int reg = 0; reg < 4; ++reg) {
    int row = r0 + khi * 4 + reg;
    if (row < NN) {
      float d = dis[row];
#pragma unroll
      for (int n = 0; n < 8; ++n) {
        int col = n * 16 + colb;
        out[(size_t)(col >> 6) * NN * 64 + (size_t)row * 64 + (col & 63)] = f2b(acc[n][reg] * d);
      }
    }
  }
}

// ---------------- aggregation (per plane): t = relu(dis*(self+sum_src)+b) ----------------
__global__ __launch_bounds__(256) void k_agg(const uint* __restrict__ hsu, const int* __restrict__ offs,
                                             const int* __restrict__ deg, const int* __restrict__ csr,
                                             const float* __restrict__ dis, const float* __restrict__ bias,
                                             uint* __restrict__ outu, int pass) {
  int half = threadIdx.x >> 5;          // 0..7: 2 nodes per wave
  int lane = threadIdx.x & 31;
  int node = blockIdx.x * 8 + half;
  if (node >= NN) return;
  const uint* hp = hsu + (size_t)pass * PLU;
  uint self = hp[(size_t)node * 32 + lane];
  float ax = lo2f(self), ay = hi2f(self);
  int beg = offs[node], cnt = deg[node];
  int i = 0;
  for (; i + 4 <= cnt; i += 4) {
    int s0 = csr[beg + i], s1 = csr[beg + i + 1], s2 = csr[beg + i + 2], s3 = csr[beg + i + 3];
    uint v0 = hp[(size_t)s0 * 32 + lane];
    uint v1 = hp[(size_t)s1 * 32 + lane];
    uint v2 = hp[(size_t)s2 * 32 + lane];
    uint v3 = hp[(size_t)s3 * 32 + lane];
    ax += lo2f(v0) + lo2f(v1) + lo2f(v2) + lo2f(v3);
    ay += hi2f(v0) + hi2f(v1) + hi2f(v2) + hi2f(v3);
  }
  for (; i < cnt; ++i) {
    uint v = hp[(size_t)csr[beg + i] * 32 + lane];
    ax += lo2f(v);
    ay += hi2f(v);
  }
  float d = dis[node];
  int f = pass * 64 + lane * 2;
  float ox = fmaxf(fmaf(d, ax, bias[f]), 0.f);
  float oy = fmaxf(fmaf(d, ay, bias[f + 1]), 0.f);
  outu[(size_t)pass * PLU + (size_t)node * 32 + lane] = (uint)f2b(ox) | ((uint)f2b(oy) << 16);
}

// ---------------- GraphNorm stats: per-(g,f) sum & sumsq partials (no atomics) ----------------
__global__ __launch_bounds__(256) void k_stats(const uint* __restrict__ t2, const int* __restrict__ gstart,
                                               float* __restrict__ acc) {
  int g = blockIdx.x >> 4, s = blockIdx.x & 15;
  int beg = gstart[g], end = gstart[g + 1];
  int f2 = threadIdx.x & 63, q = threadIdx.x >> 6;   // 4 row-groups
  int plane = f2 >> 5, off = f2 & 31;
  const uint* base = t2 + (size_t)plane * PLU;
  float sx = 0.f, qx = 0.f, sy = 0.f, qy = 0.f;
  for (int n = beg + s * 4 + q; n < end; n += 64) {
    uint v = base[(size_t)n * 32 + off];
    float a = lo2f(v), b = hi2f(v);
    sx += a; qx = fmaf(a, a, qx);
    sy += b; qy = fmaf(b, b, qy);
  }
  __shared__ float sh[4][256];
  sh[0][threadIdx.x] = sx; sh[1][threadIdx.x] = qx;
  sh[2][threadIdx.x] = sy; sh[3][threadIdx.x] = qy;
  __syncthreads();
  if (q == 0) {
#pragma unroll
    for (int qq = 1; qq < 4; ++qq) {
      int idx = (qq << 6) | f2;
      sx += sh[0][idx]; qx += sh[1][idx];
      sy += sh[2][idx]; qy += sh[3][idx];
    }
    int f = plane * 64 + off * 2;
    float* dst = acc + (size_t)(s * NG + g) * 2 * NH;
    dst[f] = sx; dst[f + 1] = sy;
    dst[NH + f] = qx; dst[NH + f + 1] = qy;
  }
}

__global__ __launch_bounds__(128) void k_fin1(const float* __restrict__ acc, const int* __restrict__ counts,
                                              const float* __restrict__ gw, const float* __restrict__ gb,
                                              const float* __restrict__ ga,
                                              float* __restrict__ Aaff, float* __restrict__ Baff) {
  int g = blockIdx.x, f = threadIdx.x;
  float sum = 0.f, sq = 0.f;
#pragma unroll 4
  for (int s = 0; s < 16; ++s) {
    const float* d = acc + (size_t)(s * NG + g) * 2 * NH;
    sum += d[f];
    sq += d[NH + f];
  }
  float cnt = fmaxf((float)counts[g], 1.f);
  float m = sum / cnt;
  float ex2 = sq / cnt;
  float a = ga[f];
  float var = ex2 - 2.f * a * m * m + a * a * m * m;
  float rstd = rsqrtf(var + EPSV);
  float A = gw[f] * rstd;
  Aaff[g * NH + f] = A;
  Baff[g * NH + f] = gb[f] - A * a * m;
}

// fused layer-2 finalize + classifier head + softmax
__global__ __launch_bounds__(128) void k_fin2head(const float* __restrict__ acc, const int* __restrict__ counts,
                                                  const float* __restrict__ gw, const float* __restrict__ gb,
                                                  const float* __restrict__ ga, const float* __restrict__ Wc,
                                                  const float* __restrict__ bc, float* __restrict__ outp) {
  __shared__ float pool[NH];
  __shared__ float lg[NC];
  int g = blockIdx.x, f = threadIdx.x;
  float sum = 0.f, sq = 0.f;
#pragma unroll 4
  for (int s = 0; s < 16; ++s) {
    const float* d = acc + (size_t)(s * NG + g) * 2 * NH;
    sum += d[f];
    sq += d[NH + f];
  }
  float cnt = fmaxf((float)counts[g], 1.f);
  float m = sum / cnt;
  float ex2 = sq / cnt;
  float a = ga[f];
  float var = ex2 - 2.f * a * m * m + a * a * m * m;
  float rstd = rsqrtf(var + EPSV);
  pool[f] = gw[f] * rstd * (m - a * m) + gb[f];
  __syncthreads();
  if (f < NC) {
    float s = bc[f];
    for (int h = 0; h < NH; ++h) s = fmaf(pool[h], Wc[h * NC + f], s);
    lg[f] = s;
  }
  __syncthreads();
  if (f == 0) {
    float mx = lg[0];
    for (int c = 1; c < NC; ++c) mx = fmaxf(mx, lg[c]);
    float ex[NC];
    float ssum = 0.f;
    for (int c = 0; c < NC; ++c) { ex[c] = __expf(lg[c] - mx); ssum += ex[c]; }
    float inv = 1.f / ssum;
    for (int c = 0; c < NC; ++c) outp[g * NC + c] = ex[c] * inv;
  }
}

// ---------------- launch ----------------
extern "C" void kernel_launch(void* const* d_in, const int* in_sizes, int n_in,
                              void* d_out, int out_size, void* d_ws, size_t ws_size,
                              hipStream_t stream) {
  const float* x   = (const float*)d_in[0];
  const int*   ei  = (const int*)d_in[1];
  const int*   bat = (const int*)d_in[2];
  const float* W1  = (const float*)d_in[3];
  const float* b1  = (const float*)d_in[4];
  const float* gw1 = (const float*)d_in[5];
  const float* gb1 = (const float*)d_in[6];
  const float* ga1 = (const float*)d_in[7];
  const float* W2  = (const float*)d_in[8];
  const float* b2  = (const float*)d_in[9];
  const float* gw2 = (const float*)d_in[10];
  const float* gb2 = (const float*)d_in[11];
  const float* ga2 = (const float*)d_in[12];
  const float* Wc  = (const float*)d_in[13];
  const float* bc  = (const float*)d_in[14];
  float* outp = (float*)d_out;

  char* ws = (char*)d_ws;
  size_t off = 0;
  auto alloc = [&](size_t b) { size_t p = off; off += (b + 255) & ~(size_t)255; return p; };
  int*    deg     = (int*)(ws + alloc((size_t)NN * 4));
  float*  dis     = (float*)(ws + alloc((size_t)NN * 4));
  int*    counts  = (int*)(ws + alloc(NG * 4));
  int*    gstart  = (int*)(ws + alloc((NG + 1) * 4));
  int*    offs    = (int*)(ws + alloc((size_t)NN * 4));
  int*    bsums   = (int*)(ws + alloc(512 * 4));
  int*    csr     = (int*)(ws + alloc((size_t)NE * 4));
  float*  statacc = (float*)(ws + alloc((size_t)16 * NG * 2 * NH * 4));   // 1 MB partials
  float*  Aaff    = (float*)(ws + alloc((size_t)NG * NH * 4));
  float*  Baff    = (float*)(ws + alloc((size_t)NG * NH * 4));
  ushort* WF1     = (ushort*)(ws + alloc((size_t)2048 * 8 * 2));
  ushort* WF2     = (ushort*)(ws + alloc((size_t)2048 * 8 * 2));
  ushort* bufA    = (ushort*)(ws + alloc((size_t)NN * NH * 2));   // 2 planes of NN x 64
  ushort* bufB    = (ushort*)(ws + alloc((size_t)NN * NH * 2));
  // sort temps alias bufA (dead before first k_gemm writes bufA): 12.8+1.6 MB <= 25.6 MB
  int2* tmp   = (int2*)bufA;
  int*  ghist = (int*)((char*)bufA + (((size_t)NE * 8 + 255) & ~(size_t)255));
  (void)ws_size; (void)in_sizes; (void)n_in; (void)out_size;

  // prep: counts/gstart via binary search (batch sorted); CSR via counting sort, rows sorted
  k_gstart2<<<1, 128, 0, stream>>>(bat, gstart, counts);
  k_hist<<<NBLK, 256, 0, stream>>>(ei, ghist);
  k_scan1g<<<NSB, 256, 0, stream>>>(ghist, bsums);
  k_scan2<<<1, 512, 0, stream>>>(bsums, NSB);
  k_scan3g<<<NSB, 256, 0, stream>>>(ghist, bsums);
  k_scatter<<<NBLK, 256, 0, stream>>>(ei, ghist, tmp);
  k_fine<<<NB, 256, 0, stream>>>(tmp, ghist, deg, offs, dis, csr);
  k_prepw<<<16, 256, 0, stream>>>(W1, WF1, W2, WF2);

  int gemm_grid = (NN + 63) / 64;   // 1563
  int agg_grid  = (NN + 7) / 8;     // 12500

  // layer 1
  k_gemm<false><<<gemm_grid, 256, 0, stream>>>(x, WF1, dis, bat, nullptr, nullptr, bufA);
  k_agg<<<agg_grid, 256, 0, stream>>>((const uint*)bufA, offs, deg, csr, dis, b1, (uint*)bufB, 0);
  k_agg<<<agg_grid, 256, 0, stream>>>((const uint*)bufA, offs, deg, csr, dis, b1, (uint*)bufB, 1);
  k_stats<<<NG * 16, 256, 0, stream>>>((const uint*)bufB, gstart, statacc);
  k_fin1<<<NG, 128, 0, stream>>>(statacc, counts, gw1, gb1, ga1, Aaff, Baff);

  // layer 2 (norm fused into GEMM A-fragment load)
  k_gemm<true><<<gemm_grid, 256, 0, stream>>>(bufB, WF2, dis, bat, Aaff, Baff, bufA);
  k_agg<<<agg_grid, 256, 0, stream>>>((const uint*)bufA, offs, deg, csr, dis, b2, (uint*)bufB, 0);
  k_agg<<<agg_grid, 256, 0, stream>>>((const uint*)bufA, offs, deg, csr, dis, b2, (uint*)bufB, 1);
  k_stats<<<NG * 16, 256, 0, stream>>>((const uint*)bufB, gstart, statacc);
  k_fin2head<<<NG, 128, 0, stream>>>(statacc, counts, gw2, gb2, ga2, Wc, bc, outp);
}